// Round 12
// baseline (28.619 us; speedup 1.0000x reference)
//
#include <hip/hip_runtime.h>

#define BEV_H 150
#define BEV_W 150
#define NCAM  6
#define CC    128
#define FH    48
#define FW    88
#define IMG_Hf 480.0f
#define IMG_Wf 800.0f
#define NPTS  24
#define YB    (FH - 1)          // 47 row-pair blocks per camera

__device__ __forceinline__ float rdlanef(float x, int l) {
    return __uint_as_float((unsigned)__builtin_amdgcn_readlane((int)__float_as_uint(x), l));
}
__device__ __forceinline__ float bflo(unsigned x) { return __uint_as_float(x << 16); }
__device__ __forceinline__ float bfhi(unsigned x) { return __uint_as_float(x & 0xffff0000u); }

// ---- repack: feat (cam, y, x, ch) f32 -> pack (cam, yb, x, rowpair[2], ch) bf16 ----
// block (cam,yb,x) = 512B: ch0-127 of row yb, then ch0-127 of row yb+1.
#define NBLK (NCAM * YB * FW)
#define NTHR (NBLK * 32)        // 32 threads x 16B per 512B block

__global__ __launch_bounds__(256) void repack_kernel(
    const float* __restrict__ feat, unsigned short* __restrict__ pack)
{
    const int t = blockIdx.x * 256 + threadIdx.x;
    if (t >= NTHR) return;
    const int blk = t >> 5;
    const int sub = t & 31;                  // 0-15: row yb, 16-31: row yb+1
    const int cam = blk / (YB * FW);
    const int rem = blk - cam * (YB * FW);
    const int yb  = rem / FW;
    const int x   = rem - yb * FW;
    const int row = yb + (sub >> 4);
    const int ch  = (sub & 15) * 8;

    const float4* src = (const float4*)(feat + ((cam * FH + row) * FW + x) * CC + ch);
    const float4 v0 = src[0];
    const float4 v1 = src[1];
    unsigned a = __float_as_uint(v0.x), b = __float_as_uint(v0.y);
    unsigned c = __float_as_uint(v0.z), d = __float_as_uint(v0.w);
    unsigned e = __float_as_uint(v1.x), f = __float_as_uint(v1.y);
    unsigned g = __float_as_uint(v1.z), h2 = __float_as_uint(v1.w);
    a = (a + 0x7fffu + ((a >> 16) & 1u)) >> 16;
    b = (b + 0x7fffu + ((b >> 16) & 1u)) >> 16;
    c = (c + 0x7fffu + ((c >> 16) & 1u)) >> 16;
    d = (d + 0x7fffu + ((d >> 16) & 1u)) >> 16;
    e = (e + 0x7fffu + ((e >> 16) & 1u)) >> 16;
    f = (f + 0x7fffu + ((f >> 16) & 1u)) >> 16;
    g = (g + 0x7fffu + ((g >> 16) & 1u)) >> 16;
    h2 = (h2 + 0x7fffu + ((h2 >> 16) & 1u)) >> 16;
    uint4 o;
    o.x = a | (b << 16); o.y = c | (d << 16);
    o.z = e | (f << 16); o.w = g | (h2 << 16);
    *(uint4*)(pack + blk * 256 + sub * 8) = o;
}

// ---- gather: 1 wave-load per valid point ----
__global__ __launch_bounds__(128, 8) void bev_sample_kernel(
    const unsigned short* __restrict__ pack,  // bf16 row-pair blocks
    const float* __restrict__ I_,
    const float* __restrict__ E_,
    const float* __restrict__ grid,
    float* __restrict__ out)
{
    const int tid  = threadIdx.x;
    const int lane = tid & 63;
    const int wv   = tid >> 6;
    const int l32  = lane & 31;

    // --- 2D-compact XCD regions (2x4 in 75x75 patch space) ---
    const int r    = blockIdx.x & 7;
    const int i    = blockIdx.x >> 3;
    const int row0 = (r < 4) ? 0 : 38;
    const int nrow = (r < 4) ? 38 : 37;
    const int c3   = r & 3;
    const int col0 = c3 * 19;
    const int wr   = (c3 == 3) ? 18 : 19;
    if (i >= nrow * wr) return;
    int ph, pw;
    if (wr == 19) { ph = i / 19; pw = i - ph * 19; }
    else          { ph = i / 18; pw = i - ph * 18; }
    ph += row0; pw += col0;

    const int h  = ph * 2 + wv;
    const int wA = pw * 2;
    const int qA = h * BEV_W + wA;

    // --- early grid loads: lanes 0-23 cell A, 32-55 cell B ---
    const bool actA = (lane < NPTS);
    const bool actB = (lane >= 32) && (lane < 32 + NPTS);
    float gx = 0.f, gy = 0.f, gz = 0.f;
    int n = 0;
    if (actA || actB) {
        n = l32 >> 2;
        const int d = l32 & 3;
        const int wc = wA + (actB ? 1 : 0);
        gx = grid[((d * 3 + 0) * BEV_H + h) * BEV_W + wc];
        gy = grid[((d * 3 + 1) * BEV_H + h) * BEV_W + wc];
        gz = grid[((d * 3 + 2) * BEV_H + h) * BEV_W + wc];
    }

    // --- cooperative l2i = I @ E[:3,:] in LDS ---
    __shared__ __align__(16) float s_l2i[NCAM][12];
    if (tid < NCAM * 12) {
        const int nn = tid / 12, rr = tid % 12;
        const int ii = rr >> 2, j = rr & 3;
        float acc = 0.f;
        #pragma unroll
        for (int k = 0; k < 3; ++k)
            acc += I_[nn * 9 + ii * 3 + k] * E_[nn * 16 + k * 4 + j];
        s_l2i[nn][rr] = acc;
    }
    __syncthreads();

    // --- projection ---
    int   iP = 0;
    float wP00 = 0.f, wP01 = 0.f, wP10 = 0.f, wP11 = 0.f;
    bool  m = false;

    if (actA || actB) {
        const float x = gx * 102.4f - 51.2f;
        const float y = gy * 102.4f - 51.2f;
        const float z = gz * 8.0f   - 5.0f;

        const float4 M0 = *(const float4*)&s_l2i[n][0];
        const float4 M1 = *(const float4*)&s_l2i[n][4];
        const float4 M2 = *(const float4*)&s_l2i[n][8];
        const float p0 = M0.x * x + M0.y * y + M0.z * z + M0.w;
        const float p1 = M1.x * x + M1.y * y + M1.z * z + M1.w;
        const float p2 = M2.x * x + M2.y * y + M2.z * z + M2.w;

        const float eps = 1e-5f;
        const float zc = fmaxf(p2, eps);
        const float u = (p0 / zc) * (1.0f / IMG_Wf);
        const float v = (p1 / zc) * (1.0f / IMG_Hf);
        m = (p2 > eps) && (u > 0.f) && (u < 1.f) && (v > 0.f) && (v < 1.f);

        const float px = u * (float)FW - 0.5f;
        const float py = v * (float)FH - 0.5f;
        const float fx0 = floorf(px), fy0 = floorf(py);
        const int x0 = (int)fx0, y0 = (int)fy0;
        const int x1 = x0 + 1,   y1 = y0 + 1;
        const float wx1 = px - fx0, wy1 = py - fy0;
        const float wx0 = 1.f - wx1, wy0 = 1.f - wy1;

        const bool vx0 = (x0 >= 0) && (x0 < FW);
        const bool vx1 = (x1 >= 0) && (x1 < FW);
        const bool vy0 = (y0 >= 0) && (y0 < FH);
        const bool vy1 = (y1 >= 0) && (y1 < FH);
        const int cx0 = min(max(x0, 0), FW - 1), cx1 = min(max(x1, 0), FW - 1);
        const int cy0 = min(max(y0, 0), FH - 1), cy1 = min(max(y1, 0), FH - 1);

        const float w0v = wx0 * wy0 * ((vx0 && vy0) ? 1.f : 0.f);  // (x0,y0)
        const float w1v = wx1 * wy0 * ((vx1 && vy0) ? 1.f : 0.f);  // (x1,y0)
        const float w2v = wx0 * wy1 * ((vx0 && vy1) ? 1.f : 0.f);  // (x0,y1)
        const float w3v = wx1 * wy1 * ((vx1 && vy1) ? 1.f : 0.f);  // (x1,y1)

        const int bx = min(max(x0, 0), FW - 2);
        const int yb = min(max(y0, 0), FH - 2);

        // column remap onto {bx, bx+1}
        const float cA0 = (cx0 == bx)     ? 1.f : 0.f;
        const float cA1 = (cx1 == bx)     ? 1.f : 0.f;
        const float cB0 = (cx0 == bx + 1) ? 1.f : 0.f;
        const float cB1 = (cx1 == bx + 1) ? 1.f : 0.f;
        const float tL = w0v * cA0 + w1v * cA1;   // top corners -> col bx
        const float tR = w0v * cB0 + w1v * cB1;   // top corners -> col bx+1
        const float bL = w2v * cA0 + w3v * cA1;   // bottom corners -> col bx
        const float bR = w2v * cB0 + w3v * cB1;

        // row remap onto {yb, yb+1}
        const float rT0 = (cy0 == yb)     ? 1.f : 0.f;
        const float rT1 = (cy1 == yb)     ? 1.f : 0.f;
        const float rB0 = (cy0 == yb + 1) ? 1.f : 0.f;
        const float rB1 = (cy1 == yb + 1) ? 1.f : 0.f;

        wP00 = tL * rT0 + bL * rT1;   // (bx,   yb)
        wP01 = tL * rB0 + bL * rB1;   // (bx,   yb+1)
        wP10 = tR * rT0 + bR * rT1;   // (bx+1, yb)
        wP11 = tR * rB0 + bR * rB1;   // (bx+1, yb+1)

        iP = ((n * YB + yb) * FW + bx) * 256;   // ushort offset of 1KB window
    }

    unsigned long long bal = __ballot(m);       // bits 0-23 = A, 32-55 = B
    const float cntA = fmaxf((float)__popcll(bal & 0xFFFFFFull), 1.f);
    const float cntB = fmaxf((float)__popcll((bal >> 32) & 0xFFFFFFull), 1.f);

    float aA[8] = {0.f, 0.f, 0.f, 0.f, 0.f, 0.f, 0.f, 0.f};
    float aB[8] = {0.f, 0.f, 0.f, 0.f, 0.f, 0.f, 0.f, 0.f};
    const int loff = 8 * lane;                  // ushort units: 16B per lane
    const bool hi16 = (lane & 16) != 0;
    const bool hi32 = (lane & 32) != 0;

    while (bal) {
        const int e = (int)__builtin_ctzll(bal);
        bal &= bal - 1;

        const int j = __builtin_amdgcn_readlane(iP, e) + loff;
        const uint4 d = *(const uint4*)(pack + j);

        const float w00 = rdlanef(wP00, e);
        const float w01 = rdlanef(wP01, e);
        const float w10 = rdlanef(wP10, e);
        const float w11 = rdlanef(wP11, e);
        const float wlo = hi16 ? w01 : w00;
        const float whi = hi16 ? w11 : w10;
        const float w   = hi32 ? whi : wlo;

        const float v0 = bflo(d.x), v1 = bfhi(d.x);
        const float v2 = bflo(d.y), v3 = bfhi(d.y);
        const float v4 = bflo(d.z), v5 = bfhi(d.z);
        const float v6 = bflo(d.w), v7 = bfhi(d.w);

        if (e < 32) {   // wave-uniform branch
            aA[0] += w * v0; aA[1] += w * v1; aA[2] += w * v2; aA[3] += w * v3;
            aA[4] += w * v4; aA[5] += w * v5; aA[6] += w * v6; aA[7] += w * v7;
        } else {
            aB[0] += w * v0; aB[1] += w * v1; aB[2] += w * v2; aB[3] += w * v3;
            aB[4] += w * v4; aB[5] += w * v5; aB[6] += w * v6; aB[7] += w * v7;
        }
    }

    // sum the 4 pixel-groups (lanes l, l+16, l+32, l+48)
    #pragma unroll
    for (int c = 0; c < 8; ++c) {
        aA[c] += __shfl_xor(aA[c], 16);
        aA[c] += __shfl_xor(aA[c], 32);
        aB[c] += __shfl_xor(aB[c], 16);
        aB[c] += __shfl_xor(aB[c], 32);
    }

    // lanes 0-15 store cell A, lanes 16-31 store cell B (8 channels each)
    if (lane < 32) {
        const bool isA = (lane < 16);
        const float inv = isA ? (1.f / cntA) : (1.f / cntB);
        const int   q   = isA ? qA : (qA + 1);
        const int   ch  = (lane & 15) * 8;
        float4 o0, o1;
        if (isA) {
            o0.x = aA[0] * inv; o0.y = aA[1] * inv; o0.z = aA[2] * inv; o0.w = aA[3] * inv;
            o1.x = aA[4] * inv; o1.y = aA[5] * inv; o1.z = aA[6] * inv; o1.w = aA[7] * inv;
        } else {
            o0.x = aB[0] * inv; o0.y = aB[1] * inv; o0.z = aB[2] * inv; o0.w = aB[3] * inv;
            o1.x = aB[4] * inv; o1.y = aB[5] * inv; o1.z = aB[6] * inv; o1.w = aB[7] * inv;
        }
        float4* dst = (float4*)(out + q * CC + ch);
        dst[0] = o0;
        dst[1] = o1;
    }
}

extern "C" void kernel_launch(void* const* d_in, const int* in_sizes, int n_in,
                              void* d_out, int out_size, void* d_ws, size_t ws_size,
                              hipStream_t stream) {
    const float* feat = (const float*)d_in[0];
    const float* I_   = (const float*)d_in[1];
    const float* E_   = (const float*)d_in[2];
    const float* grid = (const float*)d_in[3];
    float* out        = (float*)d_out;

    unsigned short* pack = (unsigned short*)d_ws;
    repack_kernel<<<(NTHR + 255) / 256, 256, 0, stream>>>(feat, pack);
    bev_sample_kernel<<<8 * 722, 128, 0, stream>>>(pack, I_, E_, grid, out);
}

// Round 13
// 27.690 us; speedup vs baseline: 1.0336x; 1.0336x over previous
//
#include <hip/hip_runtime.h>

#define BEV_H 150
#define BEV_W 150
#define NCAM  6
#define CC    128
#define FH    48
#define FW    88
#define IMG_Hf 480.0f
#define IMG_Wf 800.0f
#define NPTS  24
#define YB    (FH - 1)          // 47 row-pair blocks per camera

__device__ __forceinline__ float rdlanef(float x, int l) {
    return __uint_as_float((unsigned)__builtin_amdgcn_readlane((int)__float_as_uint(x), l));
}
__device__ __forceinline__ float bflo(unsigned x) { return __uint_as_float(x << 16); }
__device__ __forceinline__ float bfhi(unsigned x) { return __uint_as_float(x & 0xffff0000u); }

// ---- repack: feat (cam,y,x,ch) f32 -> pack (cam,yb,x,rowpair[2],ch) bf16 ----
#define NBLK (NCAM * YB * FW)
#define NTHR (NBLK * 32)

__global__ __launch_bounds__(256) void repack_kernel(
    const float* __restrict__ feat, unsigned short* __restrict__ pack)
{
    const int t = blockIdx.x * 256 + threadIdx.x;
    if (t >= NTHR) return;
    const int blk = t >> 5;
    const int sub = t & 31;                  // 0-15: row yb, 16-31: row yb+1
    const int cam = blk / (YB * FW);
    const int rem = blk - cam * (YB * FW);
    const int yb  = rem / FW;
    const int x   = rem - yb * FW;
    const int row = yb + (sub >> 4);
    const int ch  = (sub & 15) * 8;

    const float4* src = (const float4*)(feat + ((cam * FH + row) * FW + x) * CC + ch);
    const float4 v0 = src[0];
    const float4 v1 = src[1];
    unsigned a = __float_as_uint(v0.x), b = __float_as_uint(v0.y);
    unsigned c = __float_as_uint(v0.z), d = __float_as_uint(v0.w);
    unsigned e = __float_as_uint(v1.x), f = __float_as_uint(v1.y);
    unsigned g = __float_as_uint(v1.z), h2 = __float_as_uint(v1.w);
    a = (a + 0x7fffu + ((a >> 16) & 1u)) >> 16;
    b = (b + 0x7fffu + ((b >> 16) & 1u)) >> 16;
    c = (c + 0x7fffu + ((c >> 16) & 1u)) >> 16;
    d = (d + 0x7fffu + ((d >> 16) & 1u)) >> 16;
    e = (e + 0x7fffu + ((e >> 16) & 1u)) >> 16;
    f = (f + 0x7fffu + ((f >> 16) & 1u)) >> 16;
    g = (g + 0x7fffu + ((g >> 16) & 1u)) >> 16;
    h2 = (h2 + 0x7fffu + ((h2 >> 16) & 1u)) >> 16;
    uint4 o;
    o.x = a | (b << 16); o.y = c | (d << 16);
    o.z = e | (f << 16); o.w = g | (h2 << 16);
    *(uint4*)(pack + blk * 256 + sub * 8) = o;
}

// ---- gather: 1 wave-load per point, 4 loads in flight per trip ----
__global__ __launch_bounds__(128, 8) void bev_sample_kernel(
    const unsigned short* __restrict__ pack,
    const float* __restrict__ I_,
    const float* __restrict__ E_,
    const float* __restrict__ grid,
    float* __restrict__ out)
{
    const int tid  = threadIdx.x;
    const int lane = tid & 63;
    const int wv   = tid >> 6;
    const int l32  = lane & 31;

    // --- 2D-compact XCD regions (2x4 in 75x75 patch space) ---
    const int r    = blockIdx.x & 7;
    const int i    = blockIdx.x >> 3;
    const int row0 = (r < 4) ? 0 : 38;
    const int nrow = (r < 4) ? 38 : 37;
    const int c3   = r & 3;
    const int col0 = c3 * 19;
    const int wr   = (c3 == 3) ? 18 : 19;
    if (i >= nrow * wr) return;
    int ph, pw;
    if (wr == 19) { ph = i / 19; pw = i - ph * 19; }
    else          { ph = i / 18; pw = i - ph * 18; }
    ph += row0; pw += col0;

    const int h  = ph * 2 + wv;
    const int wA = pw * 2;
    const int qA = h * BEV_W + wA;

    // --- early grid loads: lanes 0-23 cell A, 32-55 cell B ---
    const bool actA = (lane < NPTS);
    const bool actB = (lane >= 32) && (lane < 32 + NPTS);
    float gx = 0.f, gy = 0.f, gz = 0.f;
    int n = 0;
    if (actA || actB) {
        n = l32 >> 2;
        const int d = l32 & 3;
        const int wc = wA + (actB ? 1 : 0);
        gx = grid[((d * 3 + 0) * BEV_H + h) * BEV_W + wc];
        gy = grid[((d * 3 + 1) * BEV_H + h) * BEV_W + wc];
        gz = grid[((d * 3 + 2) * BEV_H + h) * BEV_W + wc];
    }

    // --- cooperative l2i = I @ E[:3,:] in LDS ---
    __shared__ __align__(16) float s_l2i[NCAM][12];
    if (tid < NCAM * 12) {
        const int nn = tid / 12, rr = tid % 12;
        const int ii = rr >> 2, j = rr & 3;
        float acc = 0.f;
        #pragma unroll
        for (int k = 0; k < 3; ++k)
            acc += I_[nn * 9 + ii * 3 + k] * E_[nn * 16 + k * 4 + j];
        s_l2i[nn][rr] = acc;
    }
    __syncthreads();

    // --- projection ---
    int   iP = 0;
    float wP00 = 0.f, wP01 = 0.f, wP10 = 0.f, wP11 = 0.f;
    bool  m = false;

    if (actA || actB) {
        const float x = gx * 102.4f - 51.2f;
        const float y = gy * 102.4f - 51.2f;
        const float z = gz * 8.0f   - 5.0f;

        const float4 M0 = *(const float4*)&s_l2i[n][0];
        const float4 M1 = *(const float4*)&s_l2i[n][4];
        const float4 M2 = *(const float4*)&s_l2i[n][8];
        const float p0 = M0.x * x + M0.y * y + M0.z * z + M0.w;
        const float p1 = M1.x * x + M1.y * y + M1.z * z + M1.w;
        const float p2 = M2.x * x + M2.y * y + M2.z * z + M2.w;

        const float eps = 1e-5f;
        const float zc = fmaxf(p2, eps);
        const float u = (p0 / zc) * (1.0f / IMG_Wf);
        const float v = (p1 / zc) * (1.0f / IMG_Hf);
        m = (p2 > eps) && (u > 0.f) && (u < 1.f) && (v > 0.f) && (v < 1.f);

        const float px = u * (float)FW - 0.5f;
        const float py = v * (float)FH - 0.5f;
        const float fx0 = floorf(px), fy0 = floorf(py);
        const int x0 = (int)fx0, y0 = (int)fy0;
        const int x1 = x0 + 1,   y1 = y0 + 1;
        const float wx1 = px - fx0, wy1 = py - fy0;
        const float wx0 = 1.f - wx1, wy0 = 1.f - wy1;

        const bool vx0 = (x0 >= 0) && (x0 < FW);
        const bool vx1 = (x1 >= 0) && (x1 < FW);
        const bool vy0 = (y0 >= 0) && (y0 < FH);
        const bool vy1 = (y1 >= 0) && (y1 < FH);
        const int cx0 = min(max(x0, 0), FW - 1), cx1 = min(max(x1, 0), FW - 1);
        const int cy0 = min(max(y0, 0), FH - 1), cy1 = min(max(y1, 0), FH - 1);

        const float w0v = wx0 * wy0 * ((vx0 && vy0) ? 1.f : 0.f);
        const float w1v = wx1 * wy0 * ((vx1 && vy0) ? 1.f : 0.f);
        const float w2v = wx0 * wy1 * ((vx0 && vy1) ? 1.f : 0.f);
        const float w3v = wx1 * wy1 * ((vx1 && vy1) ? 1.f : 0.f);

        const int bx = min(max(x0, 0), FW - 2);
        const int yb = min(max(y0, 0), FH - 2);

        const float cA0 = (cx0 == bx)     ? 1.f : 0.f;
        const float cA1 = (cx1 == bx)     ? 1.f : 0.f;
        const float cB0 = (cx0 == bx + 1) ? 1.f : 0.f;
        const float cB1 = (cx1 == bx + 1) ? 1.f : 0.f;
        const float tL = w0v * cA0 + w1v * cA1;
        const float tR = w0v * cB0 + w1v * cB1;
        const float bL = w2v * cA0 + w3v * cA1;
        const float bR = w2v * cB0 + w3v * cB1;

        const float rT0 = (cy0 == yb)     ? 1.f : 0.f;
        const float rT1 = (cy1 == yb)     ? 1.f : 0.f;
        const float rB0 = (cy0 == yb + 1) ? 1.f : 0.f;
        const float rB1 = (cy1 == yb + 1) ? 1.f : 0.f;

        wP00 = tL * rT0 + bL * rT1;   // (col bx,   row yb)
        wP01 = tL * rB0 + bL * rB1;   // (col bx,   row yb+1)
        wP10 = tR * rT0 + bR * rT1;   // (col bx+1, row yb)
        wP11 = tR * rB0 + bR * rB1;   // (col bx+1, row yb+1)

        iP = ((n * YB + yb) * FW + bx) * 256;   // ushort offset of 1KB window
    }

    const unsigned long long bal = __ballot(m);
    unsigned balA = (unsigned)(bal & 0xFFFFFFull);
    unsigned balB = (unsigned)((bal >> 32) & 0xFFFFFFull);
    const float cntA = fmaxf((float)__popc(balA), 1.f);
    const float cntB = fmaxf((float)__popc(balB), 1.f);

    float aA[8] = {0.f,0.f,0.f,0.f,0.f,0.f,0.f,0.f};
    float aB[8] = {0.f,0.f,0.f,0.f,0.f,0.f,0.f,0.f};
    const int loff = 8 * lane;                  // 16B per lane within 1KB block
    const bool hi16 = (lane & 16) != 0;
    const bool hi32 = (lane & 32) != 0;

    // lane's weight for entry e: select among the 4 pixels by (hi16=row, hi32=col)
    #define SELW(e)  ({                                            \
        const float _w00 = rdlanef(wP00, (e));                     \
        const float _w01 = rdlanef(wP01, (e));                     \
        const float _w10 = rdlanef(wP10, (e));                     \
        const float _w11 = rdlanef(wP11, (e));                     \
        const float _lo = hi16 ? _w01 : _w00;                      \
        const float _hi = hi16 ? _w11 : _w10;                      \
        hi32 ? _hi : _lo; })

    #define ACC8(acc, dd, ww)                                      \
        acc[0] += (ww) * bflo((dd).x); acc[1] += (ww) * bfhi((dd).x); \
        acc[2] += (ww) * bflo((dd).y); acc[3] += (ww) * bfhi((dd).y); \
        acc[4] += (ww) * bflo((dd).z); acc[5] += (ww) * bfhi((dd).z); \
        acc[6] += (ww) * bflo((dd).w); acc[7] += (ww) * bfhi((dd).w);

    while (balA | balB) {
        int eA0 = 0, eA1 = 0, eB0 = 32, eB1 = 32;
        float sA0 = 0.f, sA1 = 0.f, sB0 = 0.f, sB1 = 0.f;
        if (balA) {
            eA0 = __builtin_ctz(balA); balA &= balA - 1; sA0 = 1.f;
            if (balA) { eA1 = __builtin_ctz(balA); balA &= balA - 1; sA1 = 1.f; }
            else eA1 = eA0;
        }
        if (balB) {
            eB0 = 32 + __builtin_ctz(balB); balB &= balB - 1; sB0 = 1.f;
            if (balB) { eB1 = 32 + __builtin_ctz(balB); balB &= balB - 1; sB1 = 1.f; }
            else eB1 = eB0;
        }

        const int jA0 = __builtin_amdgcn_readlane(iP, eA0) + loff;
        const int jA1 = __builtin_amdgcn_readlane(iP, eA1) + loff;
        const int jB0 = __builtin_amdgcn_readlane(iP, eB0) + loff;
        const int jB1 = __builtin_amdgcn_readlane(iP, eB1) + loff;

        const uint4 dA0 = *(const uint4*)(pack + jA0);
        const uint4 dA1 = *(const uint4*)(pack + jA1);
        const uint4 dB0 = *(const uint4*)(pack + jB0);
        const uint4 dB1 = *(const uint4*)(pack + jB1);

        const float wA0 = sA0 * SELW(eA0);
        const float wA1 = sA1 * SELW(eA1);
        const float wB0 = sB0 * SELW(eB0);
        const float wB1 = sB1 * SELW(eB1);

        ACC8(aA, dA0, wA0)
        ACC8(aA, dA1, wA1)
        ACC8(aB, dB0, wB0)
        ACC8(aB, dB1, wB1)
    }
    #undef SELW
    #undef ACC8

    // sum the 4 pixel-groups (lanes l, l+16, l+32, l+48)
    #pragma unroll
    for (int c = 0; c < 8; ++c) {
        aA[c] += __shfl_xor(aA[c], 16);
        aA[c] += __shfl_xor(aA[c], 32);
        aB[c] += __shfl_xor(aB[c], 16);
        aB[c] += __shfl_xor(aB[c], 32);
    }

    // lanes 0-15 store cell A, lanes 16-31 store cell B (8 channels each)
    if (lane < 32) {
        const bool isA = (lane < 16);
        const float inv = isA ? (1.f / cntA) : (1.f / cntB);
        const int   q   = isA ? qA : (qA + 1);
        const int   ch  = (lane & 15) * 8;
        float4 o0, o1;
        if (isA) {
            o0.x = aA[0]*inv; o0.y = aA[1]*inv; o0.z = aA[2]*inv; o0.w = aA[3]*inv;
            o1.x = aA[4]*inv; o1.y = aA[5]*inv; o1.z = aA[6]*inv; o1.w = aA[7]*inv;
        } else {
            o0.x = aB[0]*inv; o0.y = aB[1]*inv; o0.z = aB[2]*inv; o0.w = aB[3]*inv;
            o1.x = aB[4]*inv; o1.y = aB[5]*inv; o1.z = aB[6]*inv; o1.w = aB[7]*inv;
        }
        float4* dst = (float4*)(out + q * CC + ch);
        dst[0] = o0;
        dst[1] = o1;
    }
}

extern "C" void kernel_launch(void* const* d_in, const int* in_sizes, int n_in,
                              void* d_out, int out_size, void* d_ws, size_t ws_size,
                              hipStream_t stream) {
    const float* feat = (const float*)d_in[0];
    const float* I_   = (const float*)d_in[1];
    const float* E_   = (const float*)d_in[2];
    const float* grid = (const float*)d_in[3];
    float* out        = (float*)d_out;

    unsigned short* pack = (unsigned short*)d_ws;
    repack_kernel<<<(NTHR + 255) / 256, 256, 0, stream>>>(feat, pack);
    bev_sample_kernel<<<8 * 722, 128, 0, stream>>>(pack, I_, E_, grid, out);
}

// Round 15
// 24.734 us; speedup vs baseline: 1.1571x; 1.1195x over previous
//
#include <hip/hip_runtime.h>
#include <hip/hip_fp16.h>

#define BEV_H 150
#define BEV_W 150
#define NCAM  6
#define CC    128
#define FH    48
#define FW    88
#define IMG_Hf 480.0f
#define IMG_Wf 800.0f
#define NPTS  24
#define QTOT  (BEV_H * BEV_W)      // 22500
#define GTOT  (QTOT * NPTS)        // 540000

__device__ __forceinline__ float rdlanef(float x, int l) {
    return __uint_as_float((unsigned)__builtin_amdgcn_readlane((int)__float_as_uint(x), l));
}

// record per (point p, cell q), layout rec[p*QTOT + q], 16B:
//  x = iT (element offset of top row; -1 if masked)
//  y = iB (bottom row; 0 if masked)
//  z = half2(wTL, wTR)   w = half2(wBL, wBR)
__global__ __launch_bounds__(256) void proj_kernel(
    const float* __restrict__ I_,
    const float* __restrict__ E_,
    const float* __restrict__ grid,
    int4* __restrict__ rec)
{
    const int g = blockIdx.x * 256 + threadIdx.x;
    if (g >= GTOT) return;
    const int p = g / QTOT;        // point id 0..23
    const int q = g - p * QTOT;    // cell id (fast-varying -> coalesced)
    const int n = p >> 2;          // camera
    const int d = p & 3;           // depth

    float M[12];
    #pragma unroll
    for (int i = 0; i < 3; ++i) {
        #pragma unroll
        for (int j = 0; j < 4; ++j) {
            float acc = 0.f;
            #pragma unroll
            for (int k = 0; k < 3; ++k)
                acc += I_[n * 9 + i * 3 + k] * E_[n * 16 + k * 4 + j];
            M[i * 4 + j] = acc;
        }
    }

    const float gx = grid[(d * 3 + 0) * QTOT + q];
    const float gy = grid[(d * 3 + 1) * QTOT + q];
    const float gz = grid[(d * 3 + 2) * QTOT + q];
    const float x = gx * 102.4f - 51.2f;
    const float y = gy * 102.4f - 51.2f;
    const float z = gz * 8.0f   - 5.0f;

    const float p0 = M[0] * x + M[1] * y + M[2]  * z + M[3];
    const float p1 = M[4] * x + M[5] * y + M[6]  * z + M[7];
    const float p2 = M[8] * x + M[9] * y + M[10] * z + M[11];

    const float eps = 1e-5f;
    const float zc = fmaxf(p2, eps);
    const float u = (p0 / zc) * (1.0f / IMG_Wf);
    const float v = (p1 / zc) * (1.0f / IMG_Hf);
    const bool m = (p2 > eps) && (u > 0.f) && (u < 1.f) && (v > 0.f) && (v < 1.f);

    int4 o;
    if (m) {
        const float px = u * (float)FW - 0.5f;
        const float py = v * (float)FH - 0.5f;
        const float fx0 = floorf(px), fy0 = floorf(py);
        const int x0 = (int)fx0, y0 = (int)fy0;
        const int x1 = x0 + 1,   y1 = y0 + 1;
        const float wx1 = px - fx0, wy1 = py - fy0;
        const float wx0 = 1.f - wx1, wy0 = 1.f - wy1;

        const bool vx0 = (x0 >= 0) && (x0 < FW);
        const bool vx1 = (x1 >= 0) && (x1 < FW);
        const bool vy0 = (y0 >= 0) && (y0 < FH);
        const bool vy1 = (y1 >= 0) && (y1 < FH);
        const int cx0 = min(max(x0, 0), FW - 1), cx1 = min(max(x1, 0), FW - 1);
        const int cy0 = min(max(y0, 0), FH - 1), cy1 = min(max(y1, 0), FH - 1);

        const float w0v = wx0 * wy0 * ((vx0 && vy0) ? 1.f : 0.f);
        const float w1v = wx1 * wy0 * ((vx1 && vy0) ? 1.f : 0.f);
        const float w2v = wx0 * wy1 * ((vx0 && vy1) ? 1.f : 0.f);
        const float w3v = wx1 * wy1 * ((vx1 && vy1) ? 1.f : 0.f);

        const int bx = min(max(x0, 0), FW - 2);
        const float wTL = ((cx0 == bx)     ? w0v : 0.f) + ((cx1 == bx)     ? w1v : 0.f);
        const float wTR = ((cx0 == bx + 1) ? w0v : 0.f) + ((cx1 == bx + 1) ? w1v : 0.f);
        const float wBL = ((cx0 == bx)     ? w2v : 0.f) + ((cx1 == bx)     ? w3v : 0.f);
        const float wBR = ((cx0 == bx + 1) ? w2v : 0.f) + ((cx1 == bx + 1) ? w3v : 0.f);

        const int base = n * FH * FW;
        o.x = (base + cy0 * FW + bx) * CC;
        o.y = (base + cy1 * FW + bx) * CC;
        __half2 hT = __floats2half2_rn(wTL, wTR);
        __half2 hB = __floats2half2_rn(wBL, wBR);
        o.z = *(int*)&hT;
        o.w = *(int*)&hB;
    } else {
        o.x = -1; o.y = 0; o.z = 0; o.w = 0;
    }
    rec[g] = o;
}

// ---- gather: prologue = one 16B record load + ballot ----
__global__ __launch_bounds__(128, 8) void bev_sample_kernel(
    const int4* __restrict__ rec,
    const float* __restrict__ feat,   // (NCAM, FH, FW, C) f32
    float* __restrict__ out)
{
    const int tid  = threadIdx.x;
    const int lane = tid & 63;
    const int wv   = tid >> 6;
    const int l32  = lane & 31;
    const bool lowhalf = (lane < 32);

    // --- 2D-compact XCD regions (2x4 in 75x75 patch space) ---
    const int r    = blockIdx.x & 7;
    const int i    = blockIdx.x >> 3;
    const int row0 = (r < 4) ? 0 : 38;
    const int nrow = (r < 4) ? 38 : 37;
    const int c3   = r & 3;
    const int col0 = c3 * 19;
    const int wr   = (c3 == 3) ? 18 : 19;
    if (i >= nrow * wr) return;
    int ph, pw;
    if (wr == 19) { ph = i / 19; pw = i - ph * 19; }
    else          { ph = i / 18; pw = i - ph * 18; }
    ph += row0; pw += col0;

    const int h  = ph * 2 + wv;
    const int wA = pw * 2;
    const int qA = h * BEV_W + wA;

    // --- record load: lanes 0-23 cell A, lanes 32-55 cell B ---
    const bool actA = (lane < NPTS);
    const bool actB = (lane >= 32) && (lane < 32 + NPTS);
    bool valid = false;
    int iT = 0, iB = 0;
    unsigned wTu = 0, wBu = 0;
    if (actA || actB) {
        const int q = actB ? (qA + 1) : qA;
        const int4 rv = rec[l32 * QTOT + q];
        valid = (rv.x >= 0);
        iT = valid ? rv.x : 0;     // sanitize: dummy readlanes must stay in-bounds
        iB = rv.y;
        wTu = (unsigned)rv.z; wBu = (unsigned)rv.w;
    }

    const unsigned long long bal = __ballot(valid);
    unsigned balA = (unsigned)(bal & 0xFFFFFFull);
    unsigned balB = (unsigned)((bal >> 32) & 0xFFFFFFull);
    const float cntA = fmaxf((float)__popc(balA), 1.f);
    const float cntB = fmaxf((float)__popc(balB), 1.f);

    float aAx = 0.f, aAy = 0.f, aAz = 0.f, aAw = 0.f;
    float aBx = 0.f, aBy = 0.f, aBz = 0.f, aBw = 0.f;
    const int loff = 4 * lane;   // lanes 0-31: col bx; 32-63: col bx+1

    #define WSEL(uw) (lowhalf ? __half2float(__low2half(*(const __half2*)&(uw))) \
                              : __half2float(__high2half(*(const __half2*)&(uw))))

    while (balA | balB) {
        int eA0 = 0, eA1 = 0, eB0 = 32, eB1 = 32;
        float sA0 = 0.f, sA1 = 0.f, sB0 = 0.f, sB1 = 0.f;
        if (balA) {
            eA0 = __builtin_ctz(balA); balA &= balA - 1; sA0 = 1.f;
            if (balA) { eA1 = __builtin_ctz(balA); balA &= balA - 1; sA1 = 1.f; }
            else eA1 = eA0;
        }
        if (balB) {
            eB0 = 32 + __builtin_ctz(balB); balB &= balB - 1; sB0 = 1.f;
            if (balB) { eB1 = 32 + __builtin_ctz(balB); balB &= balB - 1; sB1 = 1.f; }
            else eB1 = eB0;
        }

        const int jTA0 = __builtin_amdgcn_readlane(iT, eA0), jBA0 = __builtin_amdgcn_readlane(iB, eA0);
        const int jTA1 = __builtin_amdgcn_readlane(iT, eA1), jBA1 = __builtin_amdgcn_readlane(iB, eA1);
        const int jTB0 = __builtin_amdgcn_readlane(iT, eB0), jBB0 = __builtin_amdgcn_readlane(iB, eB0);
        const int jTB1 = __builtin_amdgcn_readlane(iT, eB1), jBB1 = __builtin_amdgcn_readlane(iB, eB1);

        const float4 fTA0 = *(const float4*)(feat + jTA0 + loff);
        const float4 fBA0 = *(const float4*)(feat + jBA0 + loff);
        const float4 fTA1 = *(const float4*)(feat + jTA1 + loff);
        const float4 fBA1 = *(const float4*)(feat + jBA1 + loff);
        const float4 fTB0 = *(const float4*)(feat + jTB0 + loff);
        const float4 fBB0 = *(const float4*)(feat + jBB0 + loff);
        const float4 fTB1 = *(const float4*)(feat + jTB1 + loff);
        const float4 fBB1 = *(const float4*)(feat + jBB1 + loff);

        const unsigned uTA0 = (unsigned)__builtin_amdgcn_readlane((int)wTu, eA0);
        const unsigned uBA0 = (unsigned)__builtin_amdgcn_readlane((int)wBu, eA0);
        const unsigned uTA1 = (unsigned)__builtin_amdgcn_readlane((int)wTu, eA1);
        const unsigned uBA1 = (unsigned)__builtin_amdgcn_readlane((int)wBu, eA1);
        const unsigned uTB0 = (unsigned)__builtin_amdgcn_readlane((int)wTu, eB0);
        const unsigned uBB0 = (unsigned)__builtin_amdgcn_readlane((int)wBu, eB0);
        const unsigned uTB1 = (unsigned)__builtin_amdgcn_readlane((int)wTu, eB1);
        const unsigned uBB1 = (unsigned)__builtin_amdgcn_readlane((int)wBu, eB1);

        const float wTA0 = sA0 * WSEL(uTA0), wBA0 = sA0 * WSEL(uBA0);
        const float wTA1 = sA1 * WSEL(uTA1), wBA1 = sA1 * WSEL(uBA1);
        const float wTB0 = sB0 * WSEL(uTB0), wBB0 = sB0 * WSEL(uBB0);
        const float wTB1 = sB1 * WSEL(uTB1), wBB1 = sB1 * WSEL(uBB1);

        aAx += wTA0 * fTA0.x + wBA0 * fBA0.x + wTA1 * fTA1.x + wBA1 * fBA1.x;
        aAy += wTA0 * fTA0.y + wBA0 * fBA0.y + wTA1 * fTA1.y + wBA1 * fBA1.y;
        aAz += wTA0 * fTA0.z + wBA0 * fBA0.z + wTA1 * fTA1.z + wBA1 * fBA1.z;
        aAw += wTA0 * fTA0.w + wBA0 * fBA0.w + wTA1 * fTA1.w + wBA1 * fBA1.w;
        aBx += wTB0 * fTB0.x + wBB0 * fBB0.x + wTB1 * fTB1.x + wBB1 * fBB1.x;
        aBy += wTB0 * fTB0.y + wBB0 * fBB0.y + wTB1 * fTB1.y + wBB1 * fBB1.y;
        aBz += wTB0 * fTB0.z + wBB0 * fBB0.z + wTB1 * fTB1.z + wBB1 * fBB1.z;
        aBw += wTB0 * fTB0.w + wBB0 * fBB0.w + wTB1 * fTB1.w + wBB1 * fBB1.w;
    }
    #undef WSEL

    aAx += __shfl_xor(aAx, 32);  aAy += __shfl_xor(aAy, 32);
    aAz += __shfl_xor(aAz, 32);  aAw += __shfl_xor(aAw, 32);
    aBx += __shfl_xor(aBx, 32);  aBy += __shfl_xor(aBy, 32);
    aBz += __shfl_xor(aBz, 32);  aBw += __shfl_xor(aBw, 32);

    const float inv = lowhalf ? (1.f / cntA) : (1.f / cntB);
    const int   q   = lowhalf ? qA : (qA + 1);
    float4 o;
    o.x = (lowhalf ? aAx : aBx) * inv;
    o.y = (lowhalf ? aAy : aBy) * inv;
    o.z = (lowhalf ? aAz : aBz) * inv;
    o.w = (lowhalf ? aAw : aBw) * inv;
    *(float4*)(out + q * CC + 4 * l32) = o;
}

extern "C" void kernel_launch(void* const* d_in, const int* in_sizes, int n_in,
                              void* d_out, int out_size, void* d_ws, size_t ws_size,
                              hipStream_t stream) {
    const float* feat = (const float*)d_in[0];
    const float* I_   = (const float*)d_in[1];
    const float* E_   = (const float*)d_in[2];
    const float* grid = (const float*)d_in[3];
    float* out        = (float*)d_out;

    int4* rec = (int4*)d_ws;
    proj_kernel<<<(GTOT + 255) / 256, 256, 0, stream>>>(I_, E_, grid, rec);
    bev_sample_kernel<<<8 * 722, 128, 0, stream>>>(rec, feat, out);
}

// Round 16
// 18.442 us; speedup vs baseline: 1.5519x; 1.3412x over previous
//
#include <hip/hip_runtime.h>

#define BEV_H 150
#define BEV_W 150
#define NCAM  6
#define CC    128
#define FH    48
#define FW    88
#define IMG_Hf 480.0f
#define IMG_Wf 800.0f
#define NPTS  24

__device__ __forceinline__ float rdlanef(float x, int l) {
    return __uint_as_float((unsigned)__builtin_amdgcn_readlane((int)__float_as_uint(x), l));
}

// 2 entries/cell/trip (8 float4 in flight) AND forced 8 waves/SIMD (<=64 VGPR)
__global__ __launch_bounds__(128, 8) void bev_sample_kernel(
    const float* __restrict__ feat,   // (NCAM, FH, FW, C)
    const float* __restrict__ I_,
    const float* __restrict__ E_,
    const float* __restrict__ grid,   // (D, 3, BEV_H, BEV_W)
    float* __restrict__ out)          // (Q, C)
{
    const int tid  = threadIdx.x;
    const int lane = tid & 63;
    const int wv   = tid >> 6;
    const int l32  = lane & 31;
    const bool lowhalf = (lane < 32);

    // --- 2D-compact XCD regions (2x4 in 75x75 patch space) ---
    const int r    = blockIdx.x & 7;
    const int i    = blockIdx.x >> 3;
    const int row0 = (r < 4) ? 0 : 38;
    const int nrow = (r < 4) ? 38 : 37;
    const int c3   = r & 3;
    const int col0 = c3 * 19;
    const int wr   = (c3 == 3) ? 18 : 19;
    if (i >= nrow * wr) return;
    int ph, pw;
    if (wr == 19) { ph = i / 19; pw = i - ph * 19; }
    else          { ph = i / 18; pw = i - ph * 18; }
    ph += row0; pw += col0;

    const int h  = ph * 2 + wv;
    const int wA = pw * 2;
    const int qA = h * BEV_W + wA;

    // --- early grid loads ---
    const bool actA = (lane < NPTS);
    const bool actB = (lane >= 32) && (lane < 32 + NPTS);
    float gx = 0.f, gy = 0.f, gz = 0.f;
    int n = 0;
    if (actA || actB) {
        n = l32 >> 2;
        const int d = l32 & 3;
        const int wc = wA + (actB ? 1 : 0);
        gx = grid[((d * 3 + 0) * BEV_H + h) * BEV_W + wc];
        gy = grid[((d * 3 + 1) * BEV_H + h) * BEV_W + wc];
        gz = grid[((d * 3 + 2) * BEV_H + h) * BEV_W + wc];
    }

    // --- cooperative l2i = I @ E[:3,:] in LDS ---
    __shared__ __align__(16) float s_l2i[NCAM][12];
    if (tid < NCAM * 12) {
        const int nn = tid / 12, rr = tid % 12;
        const int ii = rr >> 2, j = rr & 3;
        float acc = 0.f;
        #pragma unroll
        for (int k = 0; k < 3; ++k)
            acc += I_[nn * 9 + ii * 3 + k] * E_[nn * 16 + k * 4 + j];
        s_l2i[nn][rr] = acc;
    }
    __syncthreads();

    // --- projection: lanes 0-23 = cell A, 32-55 = cell B ---
    int   iT = 0, iB = 0;
    float wTL = 0.f, wTR = 0.f, wBL = 0.f, wBR = 0.f;
    bool  m = false;

    if (actA || actB) {
        const float x = gx * 102.4f - 51.2f;
        const float y = gy * 102.4f - 51.2f;
        const float z = gz * 8.0f   - 5.0f;

        const float4 M0 = *(const float4*)&s_l2i[n][0];
        const float4 M1 = *(const float4*)&s_l2i[n][4];
        const float4 M2 = *(const float4*)&s_l2i[n][8];
        const float p0 = M0.x * x + M0.y * y + M0.z * z + M0.w;
        const float p1 = M1.x * x + M1.y * y + M1.z * z + M1.w;
        const float p2 = M2.x * x + M2.y * y + M2.z * z + M2.w;

        const float eps = 1e-5f;
        const float zc = fmaxf(p2, eps);
        const float u = (p0 / zc) * (1.0f / IMG_Wf);
        const float v = (p1 / zc) * (1.0f / IMG_Hf);
        m = (p2 > eps) && (u > 0.f) && (u < 1.f) && (v > 0.f) && (v < 1.f);

        const float px = u * (float)FW - 0.5f;
        const float py = v * (float)FH - 0.5f;
        const float fx0 = floorf(px), fy0 = floorf(py);
        const int x0 = (int)fx0, y0 = (int)fy0;
        const int x1 = x0 + 1,   y1 = y0 + 1;
        const float wx1 = px - fx0, wy1 = py - fy0;
        const float wx0 = 1.f - wx1, wy0 = 1.f - wy1;

        const bool vx0 = (x0 >= 0) && (x0 < FW);
        const bool vx1 = (x1 >= 0) && (x1 < FW);
        const bool vy0 = (y0 >= 0) && (y0 < FH);
        const bool vy1 = (y1 >= 0) && (y1 < FH);
        const int cx0 = min(max(x0, 0), FW - 1), cx1 = min(max(x1, 0), FW - 1);
        const int cy0 = min(max(y0, 0), FH - 1), cy1 = min(max(y1, 0), FH - 1);

        const float w0v = wx0 * wy0 * ((vx0 && vy0) ? 1.f : 0.f);
        const float w1v = wx1 * wy0 * ((vx1 && vy0) ? 1.f : 0.f);
        const float w2v = wx0 * wy1 * ((vx0 && vy1) ? 1.f : 0.f);
        const float w3v = wx1 * wy1 * ((vx1 && vy1) ? 1.f : 0.f);

        const int bx = min(max(x0, 0), FW - 2);
        wTL = ((cx0 == bx)     ? w0v : 0.f) + ((cx1 == bx)     ? w1v : 0.f);
        wTR = ((cx0 == bx + 1) ? w0v : 0.f) + ((cx1 == bx + 1) ? w1v : 0.f);
        wBL = ((cx0 == bx)     ? w2v : 0.f) + ((cx1 == bx)     ? w3v : 0.f);
        wBR = ((cx0 == bx + 1) ? w2v : 0.f) + ((cx1 == bx + 1) ? w3v : 0.f);

        const int base = n * FH * FW;
        iT = (base + cy0 * FW + bx) * CC;
        iB = (base + cy1 * FW + bx) * CC;
    }

    const unsigned long long bal = __ballot(m);
    unsigned balA = (unsigned)(bal & 0xFFFFFFull);
    unsigned balB = (unsigned)((bal >> 32) & 0xFFFFFFull);
    const float cntA = fmaxf((float)__popc(balA), 1.f);
    const float cntB = fmaxf((float)__popc(balB), 1.f);

    float aAx = 0.f, aAy = 0.f, aAz = 0.f, aAw = 0.f;
    float aBx = 0.f, aBy = 0.f, aBz = 0.f, aBw = 0.f;
    const int loff = 4 * lane;

    while (balA | balB) {
        int eA0 = 0, eA1 = 0, eB0 = 32, eB1 = 32;
        float sA0 = 0.f, sA1 = 0.f, sB0 = 0.f, sB1 = 0.f;
        if (balA) {
            eA0 = __builtin_ctz(balA); balA &= balA - 1; sA0 = 1.f;
            if (balA) { eA1 = __builtin_ctz(balA); balA &= balA - 1; sA1 = 1.f; }
            else eA1 = eA0;
        }
        if (balB) {
            eB0 = 32 + __builtin_ctz(balB); balB &= balB - 1; sB0 = 1.f;
            if (balB) { eB1 = 32 + __builtin_ctz(balB); balB &= balB - 1; sB1 = 1.f; }
            else eB1 = eB0;
        }

        const int jTA0 = __builtin_amdgcn_readlane(iT, eA0), jBA0 = __builtin_amdgcn_readlane(iB, eA0);
        const int jTA1 = __builtin_amdgcn_readlane(iT, eA1), jBA1 = __builtin_amdgcn_readlane(iB, eA1);
        const int jTB0 = __builtin_amdgcn_readlane(iT, eB0), jBB0 = __builtin_amdgcn_readlane(iB, eB0);
        const int jTB1 = __builtin_amdgcn_readlane(iT, eB1), jBB1 = __builtin_amdgcn_readlane(iB, eB1);

        const float4 fTA0 = *(const float4*)(feat + jTA0 + loff);
        const float4 fBA0 = *(const float4*)(feat + jBA0 + loff);
        const float4 fTA1 = *(const float4*)(feat + jTA1 + loff);
        const float4 fBA1 = *(const float4*)(feat + jBA1 + loff);
        const float4 fTB0 = *(const float4*)(feat + jTB0 + loff);
        const float4 fBB0 = *(const float4*)(feat + jBB0 + loff);
        const float4 fTB1 = *(const float4*)(feat + jTB1 + loff);
        const float4 fBB1 = *(const float4*)(feat + jBB1 + loff);

        const float wTA0 = sA0 * (lowhalf ? rdlanef(wTL, eA0) : rdlanef(wTR, eA0));
        const float wBA0 = sA0 * (lowhalf ? rdlanef(wBL, eA0) : rdlanef(wBR, eA0));
        const float wTA1 = sA1 * (lowhalf ? rdlanef(wTL, eA1) : rdlanef(wTR, eA1));
        const float wBA1 = sA1 * (lowhalf ? rdlanef(wBL, eA1) : rdlanef(wBR, eA1));
        const float wTB0 = sB0 * (lowhalf ? rdlanef(wTL, eB0) : rdlanef(wTR, eB0));
        const float wBB0 = sB0 * (lowhalf ? rdlanef(wBL, eB0) : rdlanef(wBR, eB0));
        const float wTB1 = sB1 * (lowhalf ? rdlanef(wTL, eB1) : rdlanef(wTR, eB1));
        const float wBB1 = sB1 * (lowhalf ? rdlanef(wBL, eB1) : rdlanef(wBR, eB1));

        aAx += wTA0 * fTA0.x + wBA0 * fBA0.x + wTA1 * fTA1.x + wBA1 * fBA1.x;
        aAy += wTA0 * fTA0.y + wBA0 * fBA0.y + wTA1 * fTA1.y + wBA1 * fBA1.y;
        aAz += wTA0 * fTA0.z + wBA0 * fBA0.z + wTA1 * fTA1.z + wBA1 * fBA1.z;
        aAw += wTA0 * fTA0.w + wBA0 * fBA0.w + wTA1 * fTA1.w + wBA1 * fBA1.w;
        aBx += wTB0 * fTB0.x + wBB0 * fBB0.x + wTB1 * fTB1.x + wBB1 * fBB1.x;
        aBy += wTB0 * fTB0.y + wBB0 * fBB0.y + wTB1 * fTB1.y + wBB1 * fBB1.y;
        aBz += wTB0 * fTB0.z + wBB0 * fBB0.z + wTB1 * fTB1.z + wBB1 * fBB1.z;
        aBw += wTB0 * fTB0.w + wBB0 * fBB0.w + wTB1 * fTB1.w + wBB1 * fBB1.w;
    }

    aAx += __shfl_xor(aAx, 32);  aAy += __shfl_xor(aAy, 32);
    aAz += __shfl_xor(aAz, 32);  aAw += __shfl_xor(aAw, 32);
    aBx += __shfl_xor(aBx, 32);  aBy += __shfl_xor(aBy, 32);
    aBz += __shfl_xor(aBz, 32);  aBw += __shfl_xor(aBw, 32);

    const float inv = lowhalf ? (1.f / cntA) : (1.f / cntB);
    const int   q   = lowhalf ? qA : (qA + 1);
    float4 o;
    o.x = (lowhalf ? aAx : aBx) * inv;
    o.y = (lowhalf ? aAy : aBy) * inv;
    o.z = (lowhalf ? aAz : aBz) * inv;
    o.w = (lowhalf ? aAw : aBw) * inv;
    *(float4*)(out + q * CC + 4 * l32) = o;
}

extern "C" void kernel_launch(void* const* d_in, const int* in_sizes, int n_in,
                              void* d_out, int out_size, void* d_ws, size_t ws_size,
                              hipStream_t stream) {
    const float* feat = (const float*)d_in[0];
    const float* I_   = (const float*)d_in[1];
    const float* E_   = (const float*)d_in[2];
    const float* grid = (const float*)d_in[3];
    float* out        = (float*)d_out;

    bev_sample_kernel<<<8 * 722, 128, 0, stream>>>(feat, I_, E_, grid, out);
}